// Round 1
// baseline (1313.770 us; speedup 1.0000x reference)
//
#include <hip/hip_runtime.h>

#define N_NODES 50000
#define N_EDGES 800000
#define IN_CH   151
#define HID     128
#define OUT_CH  51
#define EDIM    51

// ---------- small weight-product kernels ----------
// M0 = W_edge0 @ W0          [51,128]
// c0 = b_edge0 @ W0          [128]
// Wc = W1 @ W_out            [128,51]
__global__ void kw1(const float* __restrict__ We0, const float* __restrict__ W0,
                    const float* __restrict__ be0, const float* __restrict__ W1,
                    const float* __restrict__ Wout,
                    float* __restrict__ M0, float* __restrict__ c0, float* __restrict__ Wc) {
    int t = blockIdx.x * blockDim.x + threadIdx.x;
    if (t < 51 * 128) {
        int i = t / 128, j = t % 128;
        float a = 0.f;
        for (int k = 0; k < IN_CH; ++k) a += We0[i * IN_CH + k] * W0[k * HID + j];
        M0[t] = a;
    } else if (t < 51 * 128 + 128) {
        int j = t - 51 * 128;
        float a = 0.f;
        for (int k = 0; k < IN_CH; ++k) a += be0[k] * W0[k * HID + j];
        c0[j] = a;
    } else if (t < 51 * 128 + 128 + 128 * 51) {
        int u = t - (51 * 128 + 128);
        int i = u / OUT_CH, j = u % OUT_CH;
        float a = 0.f;
        for (int k = 0; k < HID; ++k) a += W1[i * HID + k] * Wout[k * OUT_CH + j];
        Wc[i * OUT_CH + j] = a;
    }
}

// Mc = W_edge1 @ Wc  [51,51];  cc = b_edge1 @ Wc  [51];  dd = b1 @ W_out + b_out [51]
__global__ void kw2(const float* __restrict__ We1, const float* __restrict__ be1,
                    const float* __restrict__ b1, const float* __restrict__ Wout,
                    const float* __restrict__ bout, const float* __restrict__ Wc,
                    float* __restrict__ Mc, float* __restrict__ cc, float* __restrict__ dd) {
    int t = blockIdx.x * blockDim.x + threadIdx.x;
    if (t < 51 * 51) {
        int i = t / OUT_CH, j = t % OUT_CH;
        float a = 0.f;
        for (int k = 0; k < HID; ++k) a += We1[i * HID + k] * Wc[k * OUT_CH + j];
        Mc[t] = a;
    } else if (t < 51 * 51 + 51) {
        int j = t - 51 * 51;
        float a = 0.f;
        for (int k = 0; k < HID; ++k) a += be1[k] * Wc[k * OUT_CH + j];
        cc[j] = a;
    } else if (t < 51 * 51 + 102) {
        int j = t - (51 * 51 + 51);
        float a = 0.f;
        for (int k = 0; k < HID; ++k) a += b1[k] * Wout[k * OUT_CH + j];
        dd[j] = a + bout[j];
    }
}

// ---------- edge pass: S[n] = sum_{dst=n} edge_attr[e], deg[n] = in-degree ----------
__global__ void k_edge_s(const float* __restrict__ ea, const int* __restrict__ ei,
                         float* __restrict__ S, int* __restrict__ deg) {
    int lane = threadIdx.x & 63;
    int e = blockIdx.x * 4 + (threadIdx.x >> 6);
    if (e >= N_EDGES) return;
    int dst = ei[N_EDGES + e];
    if (lane < EDIM) {
        atomicAdd(&S[dst * EDIM + lane], ea[e * EDIM + lane]);
    } else if (lane == 63) {
        atomicAdd(&deg[dst], 1);
    }
}

// ---------- layer-0 node GEMM: y = x@W0 ; hacc = y + S@M0 + (deg+1)*c0 + b0 ----------
__global__ void k_layer0(const float* __restrict__ x, const float* __restrict__ W0,
                         const float* __restrict__ b0, const float* __restrict__ S,
                         const int* __restrict__ deg, const float* __restrict__ M0,
                         const float* __restrict__ c0,
                         float* __restrict__ y, float* __restrict__ hacc) {
    int row = blockIdx.x * 8 + (threadIdx.x >> 5);
    int c = (threadIdx.x & 31) * 4;
    if (row >= N_NODES) return;
    float4 acc = make_float4(0.f, 0.f, 0.f, 0.f);
    const float* xr = x + row * IN_CH;
    for (int k = 0; k < IN_CH; ++k) {
        float xv = xr[k];
        float4 wv = *(const float4*)(W0 + k * HID + c);
        acc.x += xv * wv.x; acc.y += xv * wv.y; acc.z += xv * wv.z; acc.w += xv * wv.w;
    }
    *(float4*)(y + row * HID + c) = acc;
    const float* Sr = S + row * EDIM;
    for (int k = 0; k < EDIM; ++k) {
        float sv = Sr[k];
        float4 wv = *(const float4*)(M0 + k * HID + c);
        acc.x += sv * wv.x; acc.y += sv * wv.y; acc.z += sv * wv.z; acc.w += sv * wv.w;
    }
    float d1 = (float)(deg[row] + 1);
    float4 cv = *(const float4*)(c0 + c);
    float4 bv = *(const float4*)(b0 + c);
    acc.x += d1 * cv.x + bv.x; acc.y += d1 * cv.y + bv.y;
    acc.z += d1 * cv.z + bv.z; acc.w += d1 * cv.w + bv.w;
    *(float4*)(hacc + row * HID + c) = acc;
}

// ---------- scatter A·y into hacc ----------
__global__ void k_scatter_h(const float* __restrict__ y, const int* __restrict__ ei,
                            float* __restrict__ hacc) {
    int c = threadIdx.x & 127;
    int e = blockIdx.x * 2 + (threadIdx.x >> 7);
    if (e >= N_EDGES) return;
    int src = ei[e], dst = ei[N_EDGES + e];
    atomicAdd(&hacc[dst * HID + c], y[src * HID + c]);
}

// ---------- layer-1+out base: w = hacc@Wc ; out = w + S@Mc + (deg+1)*cc + dd ----------
__global__ void k_layer1(const float* __restrict__ hacc, const float* __restrict__ Wc,
                         const float* __restrict__ S, const int* __restrict__ deg,
                         const float* __restrict__ Mc, const float* __restrict__ cc,
                         const float* __restrict__ dd,
                         float* __restrict__ w, float* __restrict__ out) {
    int row = blockIdx.x * 4 + (threadIdx.x >> 6);
    int c = threadIdx.x & 63;
    if (row >= N_NODES || c >= OUT_CH) return;
    float a = 0.f;
    const float* hr = hacc + row * HID;
    for (int k = 0; k < HID; ++k) a += hr[k] * Wc[k * OUT_CH + c];
    w[row * OUT_CH + c] = a;
    const float* Sr = S + row * EDIM;
    for (int k = 0; k < EDIM; ++k) a += Sr[k] * Mc[k * OUT_CH + c];
    a += (float)(deg[row] + 1) * cc[c] + dd[c];
    out[row * OUT_CH + c] = a;
}

// ---------- scatter A·w into out ----------
__global__ void k_scatter_out(const float* __restrict__ w, const int* __restrict__ ei,
                              float* __restrict__ out) {
    int c = threadIdx.x & 63;
    int e = blockIdx.x * 4 + (threadIdx.x >> 6);
    if (e >= N_EDGES || c >= OUT_CH) return;
    int src = ei[e], dst = ei[N_EDGES + e];
    atomicAdd(&out[dst * OUT_CH + c], w[src * OUT_CH + c]);
}

extern "C" void kernel_launch(void* const* d_in, const int* in_sizes, int n_in,
                              void* d_out, int out_size, void* d_ws, size_t ws_size,
                              hipStream_t stream) {
    const float* x    = (const float*)d_in[0];
    const float* ea   = (const float*)d_in[1];
    const float* We0  = (const float*)d_in[2];
    const float* be0  = (const float*)d_in[3];
    const float* W0   = (const float*)d_in[4];
    const float* b0   = (const float*)d_in[5];
    const float* We1  = (const float*)d_in[6];
    const float* be1  = (const float*)d_in[7];
    const float* W1   = (const float*)d_in[8];
    const float* b1   = (const float*)d_in[9];
    const float* Wout = (const float*)d_in[10];
    const float* bout = (const float*)d_in[11];
    const int*   ei   = (const int*)d_in[12];
    float* out = (float*)d_out;

    // workspace layout (fp32 elements), 256B-aligned chunks
    char* p = (char*)d_ws;
    auto alloc = [&](size_t bytes) {
        char* r = p;
        p += (bytes + 255) & ~(size_t)255;
        return r;
    };
    float* S    = (float*)alloc((size_t)N_NODES * EDIM * 4);   // 10.2 MB
    int*   deg  = (int*)  alloc((size_t)N_NODES * 4);          // 0.2 MB (contiguous after S)
    float* y    = (float*)alloc((size_t)N_NODES * HID * 4);    // 25.6 MB
    float* hacc = (float*)alloc((size_t)N_NODES * HID * 4);    // 25.6 MB
    float* w    = (float*)alloc((size_t)N_NODES * OUT_CH * 4); // 10.2 MB
    float* M0   = (float*)alloc(51 * 128 * 4);
    float* c0   = (float*)alloc(128 * 4);
    float* Wc   = (float*)alloc(128 * 51 * 4);
    float* Mc   = (float*)alloc(51 * 51 * 4);
    float* cc   = (float*)alloc(51 * 4);
    float* dd   = (float*)alloc(51 * 4);

    // zero S and deg (S and deg are adjacent; one memset covers both)
    hipMemsetAsync(S, 0, (size_t)N_NODES * EDIM * 4, stream);
    hipMemsetAsync(deg, 0, (size_t)N_NODES * 4, stream);

    kw1<<<(51 * 128 + 128 + 128 * 51 + 255) / 256, 256, 0, stream>>>(
        We0, W0, be0, W1, Wout, M0, c0, Wc);
    kw2<<<(51 * 51 + 102 + 255) / 256, 256, 0, stream>>>(
        We1, be1, b1, Wout, bout, Wc, Mc, cc, dd);

    k_edge_s<<<(N_EDGES + 3) / 4, 256, 0, stream>>>(ea, ei, S, deg);

    k_layer0<<<(N_NODES + 7) / 8, 256, 0, stream>>>(x, W0, b0, S, deg, M0, c0, y, hacc);

    k_scatter_h<<<(N_EDGES + 1) / 2, 256, 0, stream>>>(y, ei, hacc);

    k_layer1<<<(N_NODES + 3) / 4, 256, 0, stream>>>(hacc, Wc, S, deg, Mc, cc, dd, w, out);

    k_scatter_out<<<(N_EDGES + 3) / 4, 256, 0, stream>>>(w, ei, out);
}

// Round 2
// 922.719 us; speedup vs baseline: 1.4238x; 1.4238x over previous
//
#include <hip/hip_runtime.h>

#define N_NODES 50000
#define N_EDGES 800000
#define IN_CH   151
#define HID     128
#define OUT_CH  51
#define EDIM    51
#define NBLK    ((N_NODES + 255) / 256)   // 196 scan blocks

// ---------- small weight-product kernels ----------
__global__ void kw1(const float* __restrict__ We0, const float* __restrict__ W0,
                    const float* __restrict__ be0, const float* __restrict__ W1,
                    const float* __restrict__ Wout,
                    float* __restrict__ M0, float* __restrict__ c0, float* __restrict__ Wc) {
    int t = blockIdx.x * blockDim.x + threadIdx.x;
    if (t < 51 * 128) {
        int i = t / 128, j = t % 128;
        float a = 0.f;
        for (int k = 0; k < IN_CH; ++k) a += We0[i * IN_CH + k] * W0[k * HID + j];
        M0[t] = a;
    } else if (t < 51 * 128 + 128) {
        int j = t - 51 * 128;
        float a = 0.f;
        for (int k = 0; k < IN_CH; ++k) a += be0[k] * W0[k * HID + j];
        c0[j] = a;
    } else if (t < 51 * 128 + 128 + 128 * 51) {
        int u = t - (51 * 128 + 128);
        int i = u / OUT_CH, j = u % OUT_CH;
        float a = 0.f;
        for (int k = 0; k < HID; ++k) a += W1[i * HID + k] * Wout[k * OUT_CH + j];
        Wc[i * OUT_CH + j] = a;
    }
}

__global__ void kw2(const float* __restrict__ We1, const float* __restrict__ be1,
                    const float* __restrict__ b1, const float* __restrict__ Wout,
                    const float* __restrict__ bout, const float* __restrict__ Wc,
                    float* __restrict__ Mc, float* __restrict__ cc, float* __restrict__ dd) {
    int t = blockIdx.x * blockDim.x + threadIdx.x;
    if (t < 51 * 51) {
        int i = t / OUT_CH, j = t % OUT_CH;
        float a = 0.f;
        for (int k = 0; k < HID; ++k) a += We1[i * HID + k] * Wc[k * OUT_CH + j];
        Mc[t] = a;
    } else if (t < 51 * 51 + 51) {
        int j = t - 51 * 51;
        float a = 0.f;
        for (int k = 0; k < HID; ++k) a += be1[k] * Wc[k * OUT_CH + j];
        cc[j] = a;
    } else if (t < 51 * 51 + 102) {
        int j = t - (51 * 51 + 51);
        float a = 0.f;
        for (int k = 0; k < HID; ++k) a += b1[k] * Wout[k * OUT_CH + j];
        dd[j] = a + bout[j];
    }
}

// ---------- CSR build ----------
__global__ void k_hist(const int* __restrict__ ei, int* __restrict__ deg) {
    int e = blockIdx.x * 256 + threadIdx.x;
    if (e >= N_EDGES) return;
    atomicAdd(&deg[ei[N_EDGES + e]], 1);
}

__global__ void scan1(const int* __restrict__ deg, int* __restrict__ blksum) {
    __shared__ int lds[256];
    int i = blockIdx.x * 256 + threadIdx.x;
    lds[threadIdx.x] = (i < N_NODES) ? deg[i] : 0;
    __syncthreads();
    for (int s = 128; s > 0; s >>= 1) {
        if (threadIdx.x < s) lds[threadIdx.x] += lds[threadIdx.x + s];
        __syncthreads();
    }
    if (threadIdx.x == 0) blksum[blockIdx.x] = lds[0];
}

__global__ void scan2(const int* __restrict__ blksum, int* __restrict__ blkoff) {
    __shared__ int lds[256];
    int v = (threadIdx.x < NBLK) ? blksum[threadIdx.x] : 0;
    lds[threadIdx.x] = v;
    __syncthreads();
    for (int s = 1; s < 256; s <<= 1) {
        int t = (threadIdx.x >= s) ? lds[threadIdx.x - s] : 0;
        __syncthreads();
        lds[threadIdx.x] += t;
        __syncthreads();
    }
    if (threadIdx.x < NBLK) blkoff[threadIdx.x] = lds[threadIdx.x] - v;  // exclusive
}

__global__ void scan3(const int* __restrict__ deg, const int* __restrict__ blkoff,
                      int* __restrict__ row_start, int* __restrict__ cursor) {
    __shared__ int lds[256];
    int i = blockIdx.x * 256 + threadIdx.x;
    int v = (i < N_NODES) ? deg[i] : 0;
    lds[threadIdx.x] = v;
    __syncthreads();
    for (int s = 1; s < 256; s <<= 1) {
        int t = (threadIdx.x >= s) ? lds[threadIdx.x - s] : 0;
        __syncthreads();
        lds[threadIdx.x] += t;
        __syncthreads();
    }
    if (i < N_NODES) {
        int ex = blkoff[blockIdx.x] + lds[threadIdx.x] - v;
        row_start[i] = ex;
        cursor[i] = ex;
    }
    if (blockIdx.x == 0 && threadIdx.x == 0) row_start[N_NODES] = N_EDGES;
}

__global__ void k_fill(const int* __restrict__ ei, int* __restrict__ cursor,
                       int* __restrict__ eid_sorted, int* __restrict__ src_sorted) {
    int e = blockIdx.x * 256 + threadIdx.x;
    if (e >= N_EDGES) return;
    int dst = ei[N_EDGES + e];
    int pos = atomicAdd(&cursor[dst], 1);
    eid_sorted[pos] = e;
    src_sorted[pos] = ei[e];
}

// ---------- gather aggregations (no fp32 atomics) ----------
// S[n] = sum_{e: dst=n} edge_attr[e]   (one wave per node)
__global__ void k_agg_S(const float* __restrict__ ea, const int* __restrict__ eid_sorted,
                        const int* __restrict__ row_start, float* __restrict__ S) {
    int n = blockIdx.x * 4 + (threadIdx.x >> 6);
    if (n >= N_NODES) return;
    int lane = threadIdx.x & 63;
    int n0 = row_start[n], n1 = row_start[n + 1];
    float acc = 0.f;
    for (int base = n0; base < n1; base += 64) {
        int cnt = min(64, n1 - base);
        int eid_l = (base + lane < n1) ? eid_sorted[base + lane] : 0;
        for (int t = 0; t < cnt; ++t) {
            int eid = __shfl(eid_l, t);
            if (lane < EDIM) acc += ea[(size_t)eid * EDIM + lane];
        }
    }
    if (lane < EDIM) S[(size_t)n * EDIM + lane] = acc;
}

// hacc[n] += sum_{e: dst=n} y[src[e]]   (128 lanes per node)
__global__ void k_agg_h(const float* __restrict__ y, const int* __restrict__ src_sorted,
                        const int* __restrict__ row_start, float* __restrict__ hacc) {
    int n = blockIdx.x * 2 + (threadIdx.x >> 7);
    if (n >= N_NODES) return;
    int c = threadIdx.x & 127;
    int lane = threadIdx.x & 63;
    int n0 = row_start[n], n1 = row_start[n + 1];
    float acc = 0.f;
    for (int base = n0; base < n1; base += 64) {
        int cnt = min(64, n1 - base);
        int s_l = (base + lane < n1) ? src_sorted[base + lane] : 0;
        for (int t = 0; t < cnt; ++t) {
            int s = __shfl(s_l, t);
            acc += y[(size_t)s * HID + c];
        }
    }
    hacc[(size_t)n * HID + c] += acc;
}

// out[n] += sum_{e: dst=n} w[src[e]]   (one wave per node)
__global__ void k_agg_out(const float* __restrict__ w, const int* __restrict__ src_sorted,
                          const int* __restrict__ row_start, float* __restrict__ out) {
    int n = blockIdx.x * 4 + (threadIdx.x >> 6);
    if (n >= N_NODES) return;
    int lane = threadIdx.x & 63;
    int n0 = row_start[n], n1 = row_start[n + 1];
    float acc = 0.f;
    for (int base = n0; base < n1; base += 64) {
        int cnt = min(64, n1 - base);
        int s_l = (base + lane < n1) ? src_sorted[base + lane] : 0;
        for (int t = 0; t < cnt; ++t) {
            int s = __shfl(s_l, t);
            if (lane < OUT_CH) acc += w[(size_t)s * OUT_CH + lane];
        }
    }
    if (lane < OUT_CH) out[(size_t)n * OUT_CH + lane] += acc;
}

// ---------- layer-0 node GEMM: y = x@W0 ; hacc = y + S@M0 + (deg+1)*c0 + b0 ----------
__global__ void k_layer0(const float* __restrict__ x, const float* __restrict__ W0,
                         const float* __restrict__ b0, const float* __restrict__ S,
                         const int* __restrict__ deg, const float* __restrict__ M0,
                         const float* __restrict__ c0,
                         float* __restrict__ y, float* __restrict__ hacc) {
    int row = blockIdx.x * 8 + (threadIdx.x >> 5);
    int c = (threadIdx.x & 31) * 4;
    if (row >= N_NODES) return;
    float4 acc = make_float4(0.f, 0.f, 0.f, 0.f);
    const float* xr = x + (size_t)row * IN_CH;
    for (int k = 0; k < IN_CH; ++k) {
        float xv = xr[k];
        float4 wv = *(const float4*)(W0 + k * HID + c);
        acc.x += xv * wv.x; acc.y += xv * wv.y; acc.z += xv * wv.z; acc.w += xv * wv.w;
    }
    *(float4*)(y + (size_t)row * HID + c) = acc;
    const float* Sr = S + (size_t)row * EDIM;
    for (int k = 0; k < EDIM; ++k) {
        float sv = Sr[k];
        float4 wv = *(const float4*)(M0 + k * HID + c);
        acc.x += sv * wv.x; acc.y += sv * wv.y; acc.z += sv * wv.z; acc.w += sv * wv.w;
    }
    float d1 = (float)(deg[row] + 1);
    float4 cv = *(const float4*)(c0 + c);
    float4 bv = *(const float4*)(b0 + c);
    acc.x += d1 * cv.x + bv.x; acc.y += d1 * cv.y + bv.y;
    acc.z += d1 * cv.z + bv.z; acc.w += d1 * cv.w + bv.w;
    *(float4*)(hacc + (size_t)row * HID + c) = acc;
}

// ---------- layer-1+out base: w = hacc@Wc ; out = w + S@Mc + (deg+1)*cc + dd ----------
__global__ void k_layer1(const float* __restrict__ hacc, const float* __restrict__ Wc,
                         const float* __restrict__ S, const int* __restrict__ deg,
                         const float* __restrict__ Mc, const float* __restrict__ cc,
                         const float* __restrict__ dd,
                         float* __restrict__ w, float* __restrict__ out) {
    int row = blockIdx.x * 4 + (threadIdx.x >> 6);
    int c = threadIdx.x & 63;
    if (row >= N_NODES || c >= OUT_CH) return;
    float a = 0.f;
    const float* hr = hacc + (size_t)row * HID;
    for (int k = 0; k < HID; ++k) a += hr[k] * Wc[k * OUT_CH + c];
    w[(size_t)row * OUT_CH + c] = a;
    const float* Sr = S + (size_t)row * EDIM;
    for (int k = 0; k < EDIM; ++k) a += Sr[k] * Mc[k * OUT_CH + c];
    a += (float)(deg[row] + 1) * cc[c] + dd[c];
    out[(size_t)row * OUT_CH + c] = a;
}

extern "C" void kernel_launch(void* const* d_in, const int* in_sizes, int n_in,
                              void* d_out, int out_size, void* d_ws, size_t ws_size,
                              hipStream_t stream) {
    const float* x    = (const float*)d_in[0];
    const float* ea   = (const float*)d_in[1];
    const float* We0  = (const float*)d_in[2];
    const float* be0  = (const float*)d_in[3];
    const float* W0   = (const float*)d_in[4];
    const float* b0   = (const float*)d_in[5];
    const float* We1  = (const float*)d_in[6];
    const float* be1  = (const float*)d_in[7];
    const float* W1   = (const float*)d_in[8];
    const float* b1   = (const float*)d_in[9];
    const float* Wout = (const float*)d_in[10];
    const float* bout = (const float*)d_in[11];
    const int*   ei   = (const int*)d_in[12];
    float* out = (float*)d_out;

    char* p = (char*)d_ws;
    auto alloc = [&](size_t bytes) {
        char* r = p;
        p += (bytes + 255) & ~(size_t)255;
        return r;
    };
    float* S         = (float*)alloc((size_t)N_NODES * EDIM * 4);    // 10.2 MB
    int*   deg       = (int*)  alloc((size_t)N_NODES * 4);           // 0.2 MB
    int*   row_start = (int*)  alloc((size_t)(N_NODES + 1) * 4);     // 0.2 MB
    int*   cursor    = (int*)  alloc((size_t)N_NODES * 4);           // 0.2 MB
    int*   blksum    = (int*)  alloc((size_t)NBLK * 4);
    int*   blkoff    = (int*)  alloc((size_t)NBLK * 4);
    int*   eid_srt   = (int*)  alloc((size_t)N_EDGES * 4);           // 3.2 MB
    int*   src_srt   = (int*)  alloc((size_t)N_EDGES * 4);           // 3.2 MB
    float* y         = (float*)alloc((size_t)N_NODES * HID * 4);     // 25.6 MB
    float* hacc      = (float*)alloc((size_t)N_NODES * HID * 4);     // 25.6 MB
    float* w         = (float*)alloc((size_t)N_NODES * OUT_CH * 4);  // 10.2 MB
    float* M0        = (float*)alloc(51 * 128 * 4);
    float* c0        = (float*)alloc(128 * 4);
    float* Wc        = (float*)alloc(128 * 51 * 4);
    float* Mc        = (float*)alloc(51 * 51 * 4);
    float* cc        = (float*)alloc(51 * 4);
    float* dd        = (float*)alloc(51 * 4);

    hipMemsetAsync(deg, 0, (size_t)N_NODES * 4, stream);

    kw1<<<(51 * 128 + 128 + 128 * 51 + 255) / 256, 256, 0, stream>>>(
        We0, W0, be0, W1, Wout, M0, c0, Wc);
    kw2<<<(51 * 51 + 102 + 255) / 256, 256, 0, stream>>>(
        We1, be1, b1, Wout, bout, Wc, Mc, cc, dd);

    // CSR build
    k_hist<<<(N_EDGES + 255) / 256, 256, 0, stream>>>(ei, deg);
    scan1<<<NBLK, 256, 0, stream>>>(deg, blksum);
    scan2<<<1, 256, 0, stream>>>(blksum, blkoff);
    scan3<<<NBLK, 256, 0, stream>>>(deg, blkoff, row_start, cursor);
    k_fill<<<(N_EDGES + 255) / 256, 256, 0, stream>>>(ei, cursor, eid_srt, src_srt);

    // S aggregation (gather)
    k_agg_S<<<(N_NODES + 3) / 4, 256, 0, stream>>>(ea, eid_srt, row_start, S);

    // layer 0
    k_layer0<<<(N_NODES + 7) / 8, 256, 0, stream>>>(x, W0, b0, S, deg, M0, c0, y, hacc);
    k_agg_h<<<(N_NODES + 1) / 2, 256, 0, stream>>>(y, src_srt, row_start, hacc);

    // layer 1 + output projection
    k_layer1<<<(N_NODES + 3) / 4, 256, 0, stream>>>(hacc, Wc, S, deg, Mc, cc, dd, w, out);
    k_agg_out<<<(N_NODES + 3) / 4, 256, 0, stream>>>(w, src_srt, row_start, out);
}

// Round 3
// 731.374 us; speedup vs baseline: 1.7963x; 1.2616x over previous
//
#include <hip/hip_runtime.h>

#define N_NODES 50000
#define N_EDGES 800000
#define IN_CH   151
#define HID     128
#define OUT_CH  51
#define EDIM    51
#define WPAD    52              // padded minor dim for Wc / Mc / w
#define LROW    68              // LDS transposed-tile row stride (floats)
#define NBLK    ((N_NODES + 255) / 256)   // 196 scan blocks

// ---------- small weight-product kernels ----------
// M0 = W_edge0@W0 [51,128]; c0 = b_edge0@W0 [128]; Wc = W1@W_out padded [128,52]
__global__ void kw1(const float* __restrict__ We0, const float* __restrict__ W0,
                    const float* __restrict__ be0, const float* __restrict__ W1,
                    const float* __restrict__ Wout,
                    float* __restrict__ M0, float* __restrict__ c0, float* __restrict__ Wc) {
    int t = blockIdx.x * blockDim.x + threadIdx.x;
    if (t < 51 * 128) {
        int i = t / 128, j = t % 128;
        float a = 0.f;
        for (int k = 0; k < IN_CH; ++k) a += We0[i * IN_CH + k] * W0[k * HID + j];
        M0[t] = a;
    } else if (t < 51 * 128 + 128) {
        int j = t - 51 * 128;
        float a = 0.f;
        for (int k = 0; k < IN_CH; ++k) a += be0[k] * W0[k * HID + j];
        c0[j] = a;
    } else if (t < 51 * 128 + 128 + 128 * WPAD) {
        int u = t - (51 * 128 + 128);
        int i = u / WPAD, j = u % WPAD;
        float a = 0.f;
        if (j < OUT_CH)
            for (int k = 0; k < HID; ++k) a += W1[i * HID + k] * Wout[k * OUT_CH + j];
        Wc[i * WPAD + j] = a;
    }
}

// Mc = W_edge1@Wc padded [51,52]; cc = b_edge1@Wc [51]; dd = b1@W_out + b_out [51]
__global__ void kw2(const float* __restrict__ We1, const float* __restrict__ be1,
                    const float* __restrict__ b1, const float* __restrict__ Wout,
                    const float* __restrict__ bout, const float* __restrict__ Wc,
                    float* __restrict__ Mc, float* __restrict__ cc, float* __restrict__ dd) {
    int t = blockIdx.x * blockDim.x + threadIdx.x;
    if (t < 51 * WPAD) {
        int i = t / WPAD, j = t % WPAD;
        float a = 0.f;
        if (j < OUT_CH)
            for (int k = 0; k < HID; ++k) a += We1[i * HID + k] * Wc[k * WPAD + j];
        Mc[t] = a;
    } else if (t < 51 * WPAD + 51) {
        int j = t - 51 * WPAD;
        float a = 0.f;
        for (int k = 0; k < HID; ++k) a += be1[k] * Wc[k * WPAD + j];
        cc[j] = a;
    } else if (t < 51 * WPAD + 102) {
        int j = t - (51 * WPAD + 51);
        float a = 0.f;
        for (int k = 0; k < HID; ++k) a += b1[k] * Wout[k * OUT_CH + j];
        dd[j] = a + bout[j];
    }
}

// ---------- CSR build ----------
__global__ void k_hist(const int* __restrict__ ei, int* __restrict__ deg) {
    int e = blockIdx.x * 256 + threadIdx.x;
    if (e >= N_EDGES) return;
    atomicAdd(&deg[ei[N_EDGES + e]], 1);
}

__global__ void scan1(const int* __restrict__ deg, int* __restrict__ blksum) {
    __shared__ int lds[256];
    int i = blockIdx.x * 256 + threadIdx.x;
    lds[threadIdx.x] = (i < N_NODES) ? deg[i] : 0;
    __syncthreads();
    for (int s = 128; s > 0; s >>= 1) {
        if (threadIdx.x < s) lds[threadIdx.x] += lds[threadIdx.x + s];
        __syncthreads();
    }
    if (threadIdx.x == 0) blksum[blockIdx.x] = lds[0];
}

__global__ void scan2(const int* __restrict__ blksum, int* __restrict__ blkoff) {
    __shared__ int lds[256];
    int v = (threadIdx.x < NBLK) ? blksum[threadIdx.x] : 0;
    lds[threadIdx.x] = v;
    __syncthreads();
    for (int s = 1; s < 256; s <<= 1) {
        int t = (threadIdx.x >= s) ? lds[threadIdx.x - s] : 0;
        __syncthreads();
        lds[threadIdx.x] += t;
        __syncthreads();
    }
    if (threadIdx.x < NBLK) blkoff[threadIdx.x] = lds[threadIdx.x] - v;  // exclusive
}

__global__ void scan3(const int* __restrict__ deg, const int* __restrict__ blkoff,
                      int* __restrict__ row_start, int* __restrict__ cursor) {
    __shared__ int lds[256];
    int i = blockIdx.x * 256 + threadIdx.x;
    int v = (i < N_NODES) ? deg[i] : 0;
    lds[threadIdx.x] = v;
    __syncthreads();
    for (int s = 1; s < 256; s <<= 1) {
        int t = (threadIdx.x >= s) ? lds[threadIdx.x - s] : 0;
        __syncthreads();
        lds[threadIdx.x] += t;
        __syncthreads();
    }
    if (i < N_NODES) {
        int ex = blkoff[blockIdx.x] + lds[threadIdx.x] - v;
        row_start[i] = ex;
        cursor[i] = ex;
    }
    if (blockIdx.x == 0 && threadIdx.x == 0) row_start[N_NODES] = N_EDGES;
}

__global__ void k_fill(const int* __restrict__ ei, int* __restrict__ cursor,
                       int* __restrict__ eid_sorted, int* __restrict__ src_sorted) {
    int e = blockIdx.x * 256 + threadIdx.x;
    if (e >= N_EDGES) return;
    int dst = ei[N_EDGES + e];
    int pos = atomicAdd(&cursor[dst], 1);
    eid_sorted[pos] = e;
    src_sorted[pos] = ei[e];
}

// ---------- gather aggregations ----------
// S[n] = sum_{e: dst=n} edge_attr[e]   (one wave per node)
__global__ void k_agg_S(const float* __restrict__ ea, const int* __restrict__ eid_sorted,
                        const int* __restrict__ row_start, float* __restrict__ S) {
    int n = blockIdx.x * 4 + (threadIdx.x >> 6);
    if (n >= N_NODES) return;
    int lane = threadIdx.x & 63;
    int n0 = row_start[n], n1 = row_start[n + 1];
    float acc = 0.f;
    for (int base = n0; base < n1; base += 64) {
        int cnt = min(64, n1 - base);
        int eid_l = (base + lane < n1) ? eid_sorted[base + lane] : 0;
        for (int t = 0; t < cnt; ++t) {
            int eid = __shfl(eid_l, t);
            if (lane < EDIM) acc += ea[(size_t)eid * EDIM + lane];
        }
    }
    if (lane < EDIM) S[(size_t)n * EDIM + lane] = acc;
}

// hacc[n] += sum_{e: dst=n} y[src[e]]   (one wave per node, float2 channels)
__global__ void k_agg_h(const float* __restrict__ y, const int* __restrict__ src_sorted,
                        const int* __restrict__ row_start, float* __restrict__ hacc) {
    int n = blockIdx.x * 4 + (threadIdx.x >> 6);
    if (n >= N_NODES) return;
    int lane = threadIdx.x & 63;
    int n0 = row_start[n], n1 = row_start[n + 1];
    float2 acc = make_float2(0.f, 0.f);
    for (int base = n0; base < n1; base += 64) {
        int cnt = min(64, n1 - base);
        int s_l = (base + lane < n1) ? src_sorted[base + lane] : 0;
        for (int t = 0; t < cnt; ++t) {
            int s = __shfl(s_l, t);
            float2 v = *(const float2*)(y + (size_t)s * HID + (lane << 1));
            acc.x += v.x; acc.y += v.y;
        }
    }
    float2* hp = (float2*)(hacc + (size_t)n * HID) + lane;
    float2 old = *hp;
    old.x += acc.x; old.y += acc.y;
    *hp = old;
}

// out[n] += sum_{e: dst=n} w[src[e]]   (one wave per node; w padded to 52)
__global__ void k_agg_out(const float* __restrict__ w, const int* __restrict__ src_sorted,
                          const int* __restrict__ row_start, float* __restrict__ out) {
    int n = blockIdx.x * 4 + (threadIdx.x >> 6);
    if (n >= N_NODES) return;
    int lane = threadIdx.x & 63;
    int n0 = row_start[n], n1 = row_start[n + 1];
    float acc = 0.f;
    for (int base = n0; base < n1; base += 64) {
        int cnt = min(64, n1 - base);
        int s_l = (base + lane < n1) ? src_sorted[base + lane] : 0;
        for (int t = 0; t < cnt; ++t) {
            int s = __shfl(s_l, t);
            if (lane < OUT_CH) acc += w[(size_t)s * WPAD + lane];
        }
    }
    if (lane < OUT_CH) out[(size_t)n * OUT_CH + lane] += acc;
}

// ---------- layer-0 tiled GEMM: y = x@W0 ; hacc = y + S@M0 + (deg+1)*c0 + b0 ----------
// block = 64 rows x 128 cols; thread tile 8 rows x 4 cols; x,S staged transposed in LDS.
__global__ __launch_bounds__(256) void k_layer0(
        const float* __restrict__ x, const float* __restrict__ W0,
        const float* __restrict__ b0, const float* __restrict__ S,
        const int* __restrict__ deg, const float* __restrict__ M0,
        const float* __restrict__ c0,
        float* __restrict__ y, float* __restrict__ hacc) {
    __shared__ float xT[IN_CH * LROW];   // 41.1 KB
    __shared__ float ST[EDIM * LROW];    // 13.9 KB
    int tid = threadIdx.x;
    int r_base = blockIdx.x * 64;
    for (int idx = tid; idx < 64 * IN_CH; idx += 256) {
        int r = idx / IN_CH, k = idx - r * IN_CH;
        int row = r_base + r;
        xT[k * LROW + r] = (row < N_NODES) ? x[(size_t)row * IN_CH + k] : 0.f;
    }
    for (int idx = tid; idx < 64 * EDIM; idx += 256) {
        int r = idx / EDIM, k = idx - r * EDIM;
        int row = r_base + r;
        ST[k * LROW + r] = (row < N_NODES) ? S[(size_t)row * EDIM + k] : 0.f;
    }
    __syncthreads();

    int cg = tid & 31, rg = tid >> 5;
    int c = cg * 4, r0 = rg * 8;
    float4 acc[8];
#pragma unroll
    for (int i = 0; i < 8; ++i) acc[i] = make_float4(0.f, 0.f, 0.f, 0.f);

    for (int k = 0; k < IN_CH; ++k) {
        float4 wv = *(const float4*)(W0 + k * HID + c);
        float4 a0 = *(const float4*)(&xT[k * LROW + r0]);
        float4 a1 = *(const float4*)(&xT[k * LROW + r0 + 4]);
        float ar[8] = {a0.x, a0.y, a0.z, a0.w, a1.x, a1.y, a1.z, a1.w};
#pragma unroll
        for (int i = 0; i < 8; ++i) {
            acc[i].x += ar[i] * wv.x; acc[i].y += ar[i] * wv.y;
            acc[i].z += ar[i] * wv.z; acc[i].w += ar[i] * wv.w;
        }
    }
#pragma unroll
    for (int i = 0; i < 8; ++i) {
        int row = r_base + r0 + i;
        if (row < N_NODES) *(float4*)(y + (size_t)row * HID + c) = acc[i];
    }
    for (int k = 0; k < EDIM; ++k) {
        float4 wv = *(const float4*)(M0 + k * HID + c);
        float4 a0 = *(const float4*)(&ST[k * LROW + r0]);
        float4 a1 = *(const float4*)(&ST[k * LROW + r0 + 4]);
        float ar[8] = {a0.x, a0.y, a0.z, a0.w, a1.x, a1.y, a1.z, a1.w};
#pragma unroll
        for (int i = 0; i < 8; ++i) {
            acc[i].x += ar[i] * wv.x; acc[i].y += ar[i] * wv.y;
            acc[i].z += ar[i] * wv.z; acc[i].w += ar[i] * wv.w;
        }
    }
    float4 cv = *(const float4*)(c0 + c);
    float4 bv = *(const float4*)(b0 + c);
#pragma unroll
    for (int i = 0; i < 8; ++i) {
        int row = r_base + r0 + i;
        if (row < N_NODES) {
            float d1 = (float)(deg[row] + 1);
            float4 v = acc[i];
            v.x += d1 * cv.x + bv.x; v.y += d1 * cv.y + bv.y;
            v.z += d1 * cv.z + bv.z; v.w += d1 * cv.w + bv.w;
            *(float4*)(hacc + (size_t)row * HID + c) = v;
        }
    }
}

// ---------- layer-1 tiled GEMM: w = hacc@Wc ; out = w + S@Mc + (deg+1)*cc + dd ----------
// block = 64 rows x 52 cols(padded); thread tile 4 rows x 4 cols.
__global__ __launch_bounds__(256) void k_layer1(
        const float* __restrict__ hacc, const float* __restrict__ Wc,
        const float* __restrict__ S, const int* __restrict__ deg,
        const float* __restrict__ Mc, const float* __restrict__ cc,
        const float* __restrict__ dd,
        float* __restrict__ w, float* __restrict__ out) {
    __shared__ float hT[HID * LROW];     // 34.8 KB
    __shared__ float ST[EDIM * LROW];    // 13.9 KB
    int tid = threadIdx.x;
    int r_base = blockIdx.x * 64;
    for (int idx = tid; idx < 64 * HID; idx += 256) {
        int r = idx >> 7, k = idx & 127;
        int row = r_base + r;
        hT[k * LROW + r] = (row < N_NODES) ? hacc[(size_t)row * HID + k] : 0.f;
    }
    for (int idx = tid; idx < 64 * EDIM; idx += 256) {
        int r = idx / EDIM, k = idx - r * EDIM;
        int row = r_base + r;
        ST[k * LROW + r] = (row < N_NODES) ? S[(size_t)row * EDIM + k] : 0.f;
    }
    __syncthreads();

    int cg = tid & 15, rg = tid >> 4;    // 16 col-groups (13 active), 16 row-groups
    int c = cg * 4, r0 = rg * 4;
    float4 acc[4];
#pragma unroll
    for (int i = 0; i < 4; ++i) acc[i] = make_float4(0.f, 0.f, 0.f, 0.f);
    bool live = (c < WPAD);              // cg 0..12 cover 52 padded cols

    if (c < WPAD) {
        for (int k = 0; k < HID; ++k) {
            float4 wv = *(const float4*)(Wc + k * WPAD + c);
            float4 a0 = *(const float4*)(&hT[k * LROW + r0]);
            float ar[4] = {a0.x, a0.y, a0.z, a0.w};
#pragma unroll
            for (int i = 0; i < 4; ++i) {
                acc[i].x += ar[i] * wv.x; acc[i].y += ar[i] * wv.y;
                acc[i].z += ar[i] * wv.z; acc[i].w += ar[i] * wv.w;
            }
        }
#pragma unroll
        for (int i = 0; i < 4; ++i) {
            int row = r_base + r0 + i;
            if (row < N_NODES) *(float4*)(w + (size_t)row * WPAD + c) = acc[i];
        }
        for (int k = 0; k < EDIM; ++k) {
            float4 wv = *(const float4*)(Mc + k * WPAD + c);
            float4 a0 = *(const float4*)(&ST[k * LROW + r0]);
            float ar[4] = {a0.x, a0.y, a0.z, a0.w};
#pragma unroll
            for (int i = 0; i < 4; ++i) {
                acc[i].x += ar[i] * wv.x; acc[i].y += ar[i] * wv.y;
                acc[i].z += ar[i] * wv.z; acc[i].w += ar[i] * wv.w;
            }
        }
#pragma unroll
        for (int i = 0; i < 4; ++i) {
            int row = r_base + r0 + i;
            if (row < N_NODES) {
                float d1 = (float)(deg[row] + 1);
                const float* ap = (const float*)&acc[i];
#pragma unroll
                for (int j = 0; j < 4; ++j) {
                    int col = c + j;
                    if (col < OUT_CH)
                        out[(size_t)row * OUT_CH + col] = ap[j] + d1 * cc[col] + dd[col];
                }
            }
        }
    }
    (void)live;
}

extern "C" void kernel_launch(void* const* d_in, const int* in_sizes, int n_in,
                              void* d_out, int out_size, void* d_ws, size_t ws_size,
                              hipStream_t stream) {
    const float* x    = (const float*)d_in[0];
    const float* ea   = (const float*)d_in[1];
    const float* We0  = (const float*)d_in[2];
    const float* be0  = (const float*)d_in[3];
    const float* W0   = (const float*)d_in[4];
    const float* b0   = (const float*)d_in[5];
    const float* We1  = (const float*)d_in[6];
    const float* be1  = (const float*)d_in[7];
    const float* W1   = (const float*)d_in[8];
    const float* b1   = (const float*)d_in[9];
    const float* Wout = (const float*)d_in[10];
    const float* bout = (const float*)d_in[11];
    const int*   ei   = (const int*)d_in[12];
    float* out = (float*)d_out;

    char* p = (char*)d_ws;
    auto alloc = [&](size_t bytes) {
        char* r = p;
        p += (bytes + 255) & ~(size_t)255;
        return r;
    };
    float* S         = (float*)alloc((size_t)N_NODES * EDIM * 4);    // 10.2 MB
    int*   deg       = (int*)  alloc((size_t)N_NODES * 4);
    int*   row_start = (int*)  alloc((size_t)(N_NODES + 1) * 4);
    int*   cursor    = (int*)  alloc((size_t)N_NODES * 4);
    int*   blksum    = (int*)  alloc((size_t)NBLK * 4);
    int*   blkoff    = (int*)  alloc((size_t)NBLK * 4);
    int*   eid_srt   = (int*)  alloc((size_t)N_EDGES * 4);           // 3.2 MB
    int*   src_srt   = (int*)  alloc((size_t)N_EDGES * 4);           // 3.2 MB
    float* y         = (float*)alloc((size_t)N_NODES * HID * 4);     // 25.6 MB
    float* hacc      = (float*)alloc((size_t)N_NODES * HID * 4);     // 25.6 MB
    float* w         = (float*)alloc((size_t)N_NODES * WPAD * 4);    // 10.4 MB
    float* M0        = (float*)alloc(51 * 128 * 4);
    float* c0        = (float*)alloc(128 * 4);
    float* Wc        = (float*)alloc(128 * WPAD * 4);
    float* Mc        = (float*)alloc(51 * WPAD * 4);
    float* cc        = (float*)alloc(51 * 4);
    float* dd        = (float*)alloc(51 * 4);

    hipMemsetAsync(deg, 0, (size_t)N_NODES * 4, stream);

    kw1<<<(51 * 128 + 128 + 128 * WPAD + 255) / 256, 256, 0, stream>>>(
        We0, W0, be0, W1, Wout, M0, c0, Wc);
    kw2<<<(51 * WPAD + 102 + 255) / 256, 256, 0, stream>>>(
        We1, be1, b1, Wout, bout, Wc, Mc, cc, dd);

    // CSR build
    k_hist<<<(N_EDGES + 255) / 256, 256, 0, stream>>>(ei, deg);
    scan1<<<NBLK, 256, 0, stream>>>(deg, blksum);
    scan2<<<1, 256, 0, stream>>>(blksum, blkoff);
    scan3<<<NBLK, 256, 0, stream>>>(deg, blkoff, row_start, cursor);
    k_fill<<<(N_EDGES + 255) / 256, 256, 0, stream>>>(ei, cursor, eid_srt, src_srt);

    // S aggregation (gather)
    k_agg_S<<<(N_NODES + 3) / 4, 256, 0, stream>>>(ea, eid_srt, row_start, S);

    // layer 0
    k_layer0<<<(N_NODES + 63) / 64, 256, 0, stream>>>(x, W0, b0, S, deg, M0, c0, y, hacc);
    k_agg_h<<<(N_NODES + 3) / 4, 256, 0, stream>>>(y, src_srt, row_start, hacc);

    // layer 1 + output projection
    k_layer1<<<(N_NODES + 63) / 64, 256, 0, stream>>>(hacc, Wc, S, deg, Mc, cc, dd, w, out);
    k_agg_out<<<(N_NODES + 3) / 4, 256, 0, stream>>>(w, src_srt, row_start, out);
}

// Round 4
// 675.166 us; speedup vs baseline: 1.9458x; 1.0833x over previous
//
#include <hip/hip_runtime.h>

#define N_NODES 50000
#define N_EDGES 800000
#define IN_CH   151
#define HID     128
#define OUT_CH  51
#define EDIM    51
#define WP      64              // padded minor dim for Wc / Mc / w
#define LSTR    132             // LDS staging row stride (floats), 128 rows + pad
#define NBLK    ((N_NODES + 255) / 256)   // 196 scan blocks

static __device__ __forceinline__ unsigned int f2bf(float f) {
    union { float f; unsigned int u; } v; v.f = f;
    unsigned int r = v.u + 0x7FFF + ((v.u >> 16) & 1);
    return r >> 16;
}
static __device__ __forceinline__ float bflo(unsigned int u) {
    return __uint_as_float(u << 16);
}
static __device__ __forceinline__ float bfhi(unsigned int u) {
    return __uint_as_float(u & 0xFFFF0000u);
}

// ---------- small weight-product kernels ----------
// M0 = W_edge0@W0 [51,128]; c0 = b_edge0@W0 [128]; Wc = W1@W_out padded [128,64]
__global__ void kw1(const float* __restrict__ We0, const float* __restrict__ W0,
                    const float* __restrict__ be0, const float* __restrict__ W1,
                    const float* __restrict__ Wout,
                    float* __restrict__ M0, float* __restrict__ c0, float* __restrict__ Wc) {
    int t = blockIdx.x * blockDim.x + threadIdx.x;
    if (t < 51 * 128) {
        int i = t / 128, j = t % 128;
        float a = 0.f;
        for (int k = 0; k < IN_CH; ++k) a += We0[i * IN_CH + k] * W0[k * HID + j];
        M0[t] = a;
    } else if (t < 51 * 128 + 128) {
        int j = t - 51 * 128;
        float a = 0.f;
        for (int k = 0; k < IN_CH; ++k) a += be0[k] * W0[k * HID + j];
        c0[j] = a;
    } else if (t < 51 * 128 + 128 + 128 * WP) {
        int u = t - (51 * 128 + 128);
        int i = u / WP, j = u % WP;
        float a = 0.f;
        if (j < OUT_CH)
            for (int k = 0; k < HID; ++k) a += W1[i * HID + k] * Wout[k * OUT_CH + j];
        Wc[i * WP + j] = a;
    }
}

// Mc = W_edge1@Wc padded [51,64]; cc = b_edge1@Wc [51]; dd = b1@W_out + b_out [51]
__global__ void kw2(const float* __restrict__ We1, const float* __restrict__ be1,
                    const float* __restrict__ b1, const float* __restrict__ Wout,
                    const float* __restrict__ bout, const float* __restrict__ Wc,
                    float* __restrict__ Mc, float* __restrict__ cc, float* __restrict__ dd) {
    int t = blockIdx.x * blockDim.x + threadIdx.x;
    if (t < 51 * WP) {
        int i = t / WP, j = t % WP;
        float a = 0.f;
        if (j < OUT_CH)
            for (int k = 0; k < HID; ++k) a += We1[i * HID + k] * Wc[k * WP + j];
        Mc[t] = a;
    } else if (t < 51 * WP + 51) {
        int j = t - 51 * WP;
        float a = 0.f;
        for (int k = 0; k < HID; ++k) a += be1[k] * Wc[k * WP + j];
        cc[j] = a;
    } else if (t < 51 * WP + 102) {
        int j = t - (51 * WP + 51);
        float a = 0.f;
        for (int k = 0; k < HID; ++k) a += b1[k] * Wout[k * OUT_CH + j];
        dd[j] = a + bout[j];
    }
}

// ---------- CSR build ----------
__global__ void k_hist(const int* __restrict__ ei, int* __restrict__ deg) {
    int e = blockIdx.x * 256 + threadIdx.x;
    if (e >= N_EDGES) return;
    atomicAdd(&deg[ei[N_EDGES + e]], 1);
}

__global__ void scan1(const int* __restrict__ deg, int* __restrict__ blksum) {
    __shared__ int lds[256];
    int i = blockIdx.x * 256 + threadIdx.x;
    lds[threadIdx.x] = (i < N_NODES) ? deg[i] : 0;
    __syncthreads();
    for (int s = 128; s > 0; s >>= 1) {
        if (threadIdx.x < s) lds[threadIdx.x] += lds[threadIdx.x + s];
        __syncthreads();
    }
    if (threadIdx.x == 0) blksum[blockIdx.x] = lds[0];
}

__global__ void scan2(const int* __restrict__ blksum, int* __restrict__ blkoff) {
    __shared__ int lds[256];
    int v = (threadIdx.x < NBLK) ? blksum[threadIdx.x] : 0;
    lds[threadIdx.x] = v;
    __syncthreads();
    for (int s = 1; s < 256; s <<= 1) {
        int t = (threadIdx.x >= s) ? lds[threadIdx.x - s] : 0;
        __syncthreads();
        lds[threadIdx.x] += t;
        __syncthreads();
    }
    if (threadIdx.x < NBLK) blkoff[threadIdx.x] = lds[threadIdx.x] - v;  // exclusive
}

__global__ void scan3(const int* __restrict__ deg, const int* __restrict__ blkoff,
                      int* __restrict__ row_start, int* __restrict__ cursor) {
    __shared__ int lds[256];
    int i = blockIdx.x * 256 + threadIdx.x;
    int v = (i < N_NODES) ? deg[i] : 0;
    lds[threadIdx.x] = v;
    __syncthreads();
    for (int s = 1; s < 256; s <<= 1) {
        int t = (threadIdx.x >= s) ? lds[threadIdx.x - s] : 0;
        __syncthreads();
        lds[threadIdx.x] += t;
        __syncthreads();
    }
    if (i < N_NODES) {
        int ex = blkoff[blockIdx.x] + lds[threadIdx.x] - v;
        row_start[i] = ex;
        cursor[i] = ex;
    }
    if (blockIdx.x == 0 && threadIdx.x == 0) row_start[N_NODES] = N_EDGES;
}

__global__ void k_fill(const int* __restrict__ ei, int* __restrict__ cursor,
                       int* __restrict__ eid_sorted, int* __restrict__ src_sorted) {
    int e = blockIdx.x * 256 + threadIdx.x;
    if (e >= N_EDGES) return;
    int dst = ei[N_EDGES + e];
    int pos = atomicAdd(&cursor[dst], 1);
    eid_sorted[pos] = e;
    src_sorted[pos] = ei[e];
}

// ---------- gather aggregations (4-deep MLP unroll) ----------
// S[n] = sum_{e: dst=n} edge_attr[e]
__global__ void k_agg_S(const float* __restrict__ ea, const int* __restrict__ eid_sorted,
                        const int* __restrict__ row_start, float* __restrict__ S) {
    int n = blockIdx.x * 4 + (threadIdx.x >> 6);
    if (n >= N_NODES) return;
    int lane = threadIdx.x & 63;
    int n0 = row_start[n], n1 = row_start[n + 1];
    float acc = 0.f;
    bool act = lane < EDIM;
    for (int base = n0; base < n1; base += 64) {
        int cnt = min(64, n1 - base);
        int eid_l = (base + lane < n1) ? eid_sorted[base + lane] : 0;
        int t = 0;
        for (; t + 4 <= cnt; t += 4) {
            int e0 = __shfl(eid_l, t), e1 = __shfl(eid_l, t + 1);
            int e2 = __shfl(eid_l, t + 2), e3 = __shfl(eid_l, t + 3);
            float v0 = act ? ea[(size_t)e0 * EDIM + lane] : 0.f;
            float v1 = act ? ea[(size_t)e1 * EDIM + lane] : 0.f;
            float v2 = act ? ea[(size_t)e2 * EDIM + lane] : 0.f;
            float v3 = act ? ea[(size_t)e3 * EDIM + lane] : 0.f;
            acc += v0 + v1 + v2 + v3;
        }
        for (; t < cnt; ++t) {
            int e0 = __shfl(eid_l, t);
            if (act) acc += ea[(size_t)e0 * EDIM + lane];
        }
    }
    if (act) S[(size_t)n * EDIM + lane] = acc;
}

// hacc[n] += sum_{e: dst=n} y[src[e]]   (y stored bf16, 2 ch per lane)
__global__ void k_agg_h(const unsigned int* __restrict__ yb, const int* __restrict__ src_sorted,
                        const int* __restrict__ row_start, float* __restrict__ hacc) {
    int n = blockIdx.x * 4 + (threadIdx.x >> 6);
    if (n >= N_NODES) return;
    int lane = threadIdx.x & 63;
    int n0 = row_start[n], n1 = row_start[n + 1];
    float2 acc = make_float2(0.f, 0.f);
    for (int base = n0; base < n1; base += 64) {
        int cnt = min(64, n1 - base);
        int s_l = (base + lane < n1) ? src_sorted[base + lane] : 0;
        int t = 0;
        for (; t + 4 <= cnt; t += 4) {
            int s0 = __shfl(s_l, t), s1 = __shfl(s_l, t + 1);
            int s2 = __shfl(s_l, t + 2), s3 = __shfl(s_l, t + 3);
            unsigned int v0 = yb[(size_t)s0 * 64 + lane];
            unsigned int v1 = yb[(size_t)s1 * 64 + lane];
            unsigned int v2 = yb[(size_t)s2 * 64 + lane];
            unsigned int v3 = yb[(size_t)s3 * 64 + lane];
            acc.x += bflo(v0) + bflo(v1) + bflo(v2) + bflo(v3);
            acc.y += bfhi(v0) + bfhi(v1) + bfhi(v2) + bfhi(v3);
        }
        for (; t < cnt; ++t) {
            int s0 = __shfl(s_l, t);
            unsigned int v0 = yb[(size_t)s0 * 64 + lane];
            acc.x += bflo(v0); acc.y += bfhi(v0);
        }
    }
    float2* hp = (float2*)(hacc + (size_t)n * HID) + lane;
    float2 old = *hp;
    old.x += acc.x; old.y += acc.y;
    *hp = old;
}

// out[n] += sum_{e: dst=n} w[src[e]]   (w stored bf16, padded to 64)
__global__ void k_agg_out(const unsigned short* __restrict__ wb, const int* __restrict__ src_sorted,
                          const int* __restrict__ row_start, float* __restrict__ out) {
    int n = blockIdx.x * 4 + (threadIdx.x >> 6);
    if (n >= N_NODES) return;
    int lane = threadIdx.x & 63;
    int n0 = row_start[n], n1 = row_start[n + 1];
    float acc = 0.f;
    bool act = lane < OUT_CH;
    for (int base = n0; base < n1; base += 64) {
        int cnt = min(64, n1 - base);
        int s_l = (base + lane < n1) ? src_sorted[base + lane] : 0;
        int t = 0;
        for (; t + 4 <= cnt; t += 4) {
            int s0 = __shfl(s_l, t), s1 = __shfl(s_l, t + 1);
            int s2 = __shfl(s_l, t + 2), s3 = __shfl(s_l, t + 3);
            unsigned int v0 = act ? wb[(size_t)s0 * WP + lane] : 0u;
            unsigned int v1 = act ? wb[(size_t)s1 * WP + lane] : 0u;
            unsigned int v2 = act ? wb[(size_t)s2 * WP + lane] : 0u;
            unsigned int v3 = act ? wb[(size_t)s3 * WP + lane] : 0u;
            acc += bflo(v0) + bflo(v1) + bflo(v2) + bflo(v3);
        }
        for (; t < cnt; ++t) {
            int s0 = __shfl(s_l, t);
            if (act) acc += bflo((unsigned int)wb[(size_t)s0 * WP + lane]);
        }
    }
    if (act) out[(size_t)n * OUT_CH + lane] += acc;
}

// ---------- layer-0 tiled GEMM: y(bf16) = x@W0 ; hacc = y + S@M0 + (deg+1)*c0 + b0 ----------
// block = 128 rows x 128 cols; thread tile 8x8; k staged in 64-chunks (LDS 33.8 KB).
__global__ __launch_bounds__(256, 4) void k_layer0(
        const float* __restrict__ x, const float* __restrict__ W0,
        const float* __restrict__ b0, const float* __restrict__ S,
        const int* __restrict__ deg, const float* __restrict__ M0,
        const float* __restrict__ c0,
        unsigned int* __restrict__ yb, float* __restrict__ hacc) {
    __shared__ float aT[64 * LSTR];   // 33,792 B
    int tid = threadIdx.x;
    int r_base = blockIdx.x * 128;
    int cg = tid & 15, rg = tid >> 4;
    int c = cg * 8, r0 = rg * 8;

    float4 accA[8], accB[8];
#pragma unroll
    for (int i = 0; i < 8; ++i) {
        accA[i] = make_float4(0.f, 0.f, 0.f, 0.f);
        accB[i] = make_float4(0.f, 0.f, 0.f, 0.f);
    }

    // ---- x phases: k = 0..150 in chunks of 64 ----
    for (int p = 0; p < 3; ++p) {
        int koff = p * 64;
        int chunk = min(64, IN_CH - koff);
        __syncthreads();
        for (int idx = tid; idx < 128 * 64; idx += 256) {
            int r = idx >> 6, kk = idx & 63;
            if (kk >= chunk) continue;
            int row = r_base + r;
            aT[kk * LSTR + r] = (row < N_NODES) ? x[(size_t)row * IN_CH + koff + kk] : 0.f;
        }
        __syncthreads();
#pragma unroll 4
        for (int kk = 0; kk < chunk; ++kk) {
            int k = koff + kk;
            float4 wv0 = *(const float4*)(W0 + k * HID + c);
            float4 wv1 = *(const float4*)(W0 + k * HID + c + 4);
            float4 a0 = *(const float4*)(&aT[kk * LSTR + r0]);
            float4 a1 = *(const float4*)(&aT[kk * LSTR + r0 + 4]);
            float ar[8] = {a0.x, a0.y, a0.z, a0.w, a1.x, a1.y, a1.z, a1.w};
#pragma unroll
            for (int i = 0; i < 8; ++i) {
                accA[i].x += ar[i] * wv0.x; accA[i].y += ar[i] * wv0.y;
                accA[i].z += ar[i] * wv0.z; accA[i].w += ar[i] * wv0.w;
                accB[i].x += ar[i] * wv1.x; accB[i].y += ar[i] * wv1.y;
                accB[i].z += ar[i] * wv1.z; accB[i].w += ar[i] * wv1.w;
            }
        }
    }

    // ---- store y as bf16 ----
#pragma unroll
    for (int i = 0; i < 8; ++i) {
        int row = r_base + r0 + i;
        if (row < N_NODES) {
            uint4 pk;
            pk.x = f2bf(accA[i].x) | (f2bf(accA[i].y) << 16);
            pk.y = f2bf(accA[i].z) | (f2bf(accA[i].w) << 16);
            pk.z = f2bf(accB[i].x) | (f2bf(accB[i].y) << 16);
            pk.w = f2bf(accB[i].z) | (f2bf(accB[i].w) << 16);
            *(uint4*)(yb + (size_t)row * 64 + (c >> 1)) = pk;
        }
    }

    // ---- S phase: k = 0..50 ----
    __syncthreads();
    for (int idx = tid; idx < 128 * 64; idx += 256) {
        int r = idx >> 6, kk = idx & 63;
        if (kk >= EDIM) continue;
        int row = r_base + r;
        aT[kk * LSTR + r] = (row < N_NODES) ? S[(size_t)row * EDIM + kk] : 0.f;
    }
    __syncthreads();
#pragma unroll 4
    for (int kk = 0; kk < EDIM; ++kk) {
        float4 wv0 = *(const float4*)(M0 + kk * HID + c);
        float4 wv1 = *(const float4*)(M0 + kk * HID + c + 4);
        float4 a0 = *(const float4*)(&aT[kk * LSTR + r0]);
        float4 a1 = *(const float4*)(&aT[kk * LSTR + r0 + 4]);
        float ar[8] = {a0.x, a0.y, a0.z, a0.w, a1.x, a1.y, a1.z, a1.w};
#pragma unroll
        for (int i = 0; i < 8; ++i) {
            accA[i].x += ar[i] * wv0.x; accA[i].y += ar[i] * wv0.y;
            accA[i].z += ar[i] * wv0.z; accA[i].w += ar[i] * wv0.w;
            accB[i].x += ar[i] * wv1.x; accB[i].y += ar[i] * wv1.y;
            accB[i].z += ar[i] * wv1.z; accB[i].w += ar[i] * wv1.w;
        }
    }

    // ---- epilogue: hacc = acc + (deg+1)*c0 + b0 (fp32) ----
    float4 cv0 = *(const float4*)(c0 + c);
    float4 cv1 = *(const float4*)(c0 + c + 4);
    float4 bv0 = *(const float4*)(b0 + c);
    float4 bv1 = *(const float4*)(b0 + c + 4);
#pragma unroll
    for (int i = 0; i < 8; ++i) {
        int row = r_base + r0 + i;
        if (row < N_NODES) {
            float d1 = (float)(deg[row] + 1);
            float4 vA = accA[i], vB = accB[i];
            vA.x += d1 * cv0.x + bv0.x; vA.y += d1 * cv0.y + bv0.y;
            vA.z += d1 * cv0.z + bv0.z; vA.w += d1 * cv0.w + bv0.w;
            vB.x += d1 * cv1.x + bv1.x; vB.y += d1 * cv1.y + bv1.y;
            vB.z += d1 * cv1.z + bv1.z; vB.w += d1 * cv1.w + bv1.w;
            *(float4*)(hacc + (size_t)row * HID + c) = vA;
            *(float4*)(hacc + (size_t)row * HID + c + 4) = vB;
        }
    }
}

// ---------- layer-1 tiled GEMM: w(bf16) = hacc@Wc ; out = w + S@Mc + (deg+1)*cc + dd ----------
// block = 128 rows x 64 cols (52 live); thread tile 8x4.
__global__ __launch_bounds__(256, 4) void k_layer1(
        const float* __restrict__ hacc, const float* __restrict__ Wc,
        const float* __restrict__ S, const int* __restrict__ deg,
        const float* __restrict__ Mc, const float* __restrict__ cc,
        const float* __restrict__ dd,
        unsigned int* __restrict__ wb, float* __restrict__ out) {
    __shared__ float aT[64 * LSTR];
    int tid = threadIdx.x;
    int r_base = blockIdx.x * 128;
    int cg = tid & 15, rg = tid >> 4;
    int c = cg * 4, r0 = rg * 8;

    float4 acc[8];
#pragma unroll
    for (int i = 0; i < 8; ++i) acc[i] = make_float4(0.f, 0.f, 0.f, 0.f);

    // ---- h phases: k = 0..127 in chunks of 64 ----
    for (int p = 0; p < 2; ++p) {
        int koff = p * 64;
        __syncthreads();
        for (int idx = tid; idx < 128 * 64; idx += 256) {
            int r = idx >> 6, kk = idx & 63;
            int row = r_base + r;
            aT[kk * LSTR + r] = (row < N_NODES) ? hacc[(size_t)row * HID + koff + kk] : 0.f;
        }
        __syncthreads();
#pragma unroll 4
        for (int kk = 0; kk < 64; ++kk) {
            int k = koff + kk;
            float4 wv = *(const float4*)(Wc + k * WP + c);
            float4 a0 = *(const float4*)(&aT[kk * LSTR + r0]);
            float4 a1 = *(const float4*)(&aT[kk * LSTR + r0 + 4]);
            float ar[8] = {a0.x, a0.y, a0.z, a0.w, a1.x, a1.y, a1.z, a1.w};
#pragma unroll
            for (int i = 0; i < 8; ++i) {
                acc[i].x += ar[i] * wv.x; acc[i].y += ar[i] * wv.y;
                acc[i].z += ar[i] * wv.z; acc[i].w += ar[i] * wv.w;
            }
        }
    }

    // ---- store w as bf16 (padded 64) ----
#pragma unroll
    for (int i = 0; i < 8; ++i) {
        int row = r_base + r0 + i;
        if (row < N_NODES) {
            uint2 pk;
            pk.x = f2bf(acc[i].x) | (f2bf(acc[i].y) << 16);
            pk.y = f2bf(acc[i].z) | (f2bf(acc[i].w) << 16);
            *(uint2*)(wb + (size_t)row * 32 + (c >> 1)) = pk;
        }
    }

    // ---- S phase ----
    __syncthreads();
    for (int idx = tid; idx < 128 * 64; idx += 256) {
        int r = idx >> 6, kk = idx & 63;
        if (kk >= EDIM) continue;
        int row = r_base + r;
        aT[kk * LSTR + r] = (row < N_NODES) ? S[(size_t)row * EDIM + kk] : 0.f;
    }
    __syncthreads();
#pragma unroll 4
    for (int kk = 0; kk < EDIM; ++kk) {
        float4 wv = *(const float4*)(Mc + kk * WP + c);
        float4 a0 = *(const float4*)(&aT[kk * LSTR + r0]);
        float4 a1 = *(const float4*)(&aT[kk * LSTR + r0 + 4]);
        float ar[8] = {a0.x, a0.y, a0.z, a0.w, a1.x, a1.y, a1.z, a1.w};
#pragma unroll
        for (int i = 0; i < 8; ++i) {
            acc[i].x += ar[i] * wv.x; acc[i].y += ar[i] * wv.y;
            acc[i].z += ar[i] * wv.z; acc[i].w += ar[i] * wv.w;
        }
    }

    // ---- epilogue: out = acc + (deg+1)*cc + dd, cols < 51 ----
    if (c < OUT_CH) {
        float cv[4], dv[4];
#pragma unroll
        for (int j = 0; j < 4; ++j) {
            int col = c + j;
            cv[j] = (col < OUT_CH) ? cc[col] : 0.f;
            dv[j] = (col < OUT_CH) ? dd[col] : 0.f;
        }
#pragma unroll
        for (int i = 0; i < 8; ++i) {
            int row = r_base + r0 + i;
            if (row < N_NODES) {
                float d1 = (float)(deg[row] + 1);
                const float* ap = (const float*)&acc[i];
#pragma unroll
                for (int j = 0; j < 4; ++j) {
                    int col = c + j;
                    if (col < OUT_CH)
                        out[(size_t)row * OUT_CH + col] = ap[j] + d1 * cv[j] + dv[j];
                }
            }
        }
    }
}

extern "C" void kernel_launch(void* const* d_in, const int* in_sizes, int n_in,
                              void* d_out, int out_size, void* d_ws, size_t ws_size,
                              hipStream_t stream) {
    const float* x    = (const float*)d_in[0];
    const float* ea   = (const float*)d_in[1];
    const float* We0  = (const float*)d_in[2];
    const float* be0  = (const float*)d_in[3];
    const float* W0   = (const float*)d_in[4];
    const float* b0   = (const float*)d_in[5];
    const float* We1  = (const float*)d_in[6];
    const float* be1  = (const float*)d_in[7];
    const float* W1   = (const float*)d_in[8];
    const float* b1   = (const float*)d_in[9];
    const float* Wout = (const float*)d_in[10];
    const float* bout = (const float*)d_in[11];
    const int*   ei   = (const int*)d_in[12];
    float* out = (float*)d_out;

    char* p = (char*)d_ws;
    auto alloc = [&](size_t bytes) {
        char* r = p;
        p += (bytes + 255) & ~(size_t)255;
        return r;
    };
    float* S         = (float*)alloc((size_t)N_NODES * EDIM * 4);    // 10.2 MB
    int*   deg       = (int*)  alloc((size_t)N_NODES * 4);
    int*   row_start = (int*)  alloc((size_t)(N_NODES + 1) * 4);
    int*   cursor    = (int*)  alloc((size_t)N_NODES * 4);
    int*   blksum    = (int*)  alloc((size_t)NBLK * 4);
    int*   blkoff    = (int*)  alloc((size_t)NBLK * 4);
    int*   eid_srt   = (int*)  alloc((size_t)N_EDGES * 4);           // 3.2 MB
    int*   src_srt   = (int*)  alloc((size_t)N_EDGES * 4);           // 3.2 MB
    unsigned int* yb = (unsigned int*)alloc((size_t)N_NODES * 64 * 4);  // y bf16: 12.8 MB
    float* hacc      = (float*)alloc((size_t)N_NODES * HID * 4);     // 25.6 MB
    unsigned int* wb = (unsigned int*)alloc((size_t)N_NODES * 32 * 4);  // w bf16: 6.4 MB
    float* M0        = (float*)alloc(51 * 128 * 4);
    float* c0        = (float*)alloc(128 * 4);
    float* Wc        = (float*)alloc(128 * WP * 4);
    float* Mc        = (float*)alloc(51 * WP * 4);
    float* cc        = (float*)alloc(51 * 4);
    float* dd        = (float*)alloc(51 * 4);

    hipMemsetAsync(deg, 0, (size_t)N_NODES * 4, stream);

    kw1<<<(51 * 128 + 128 + 128 * WP + 255) / 256, 256, 0, stream>>>(
        We0, W0, be0, W1, Wout, M0, c0, Wc);
    kw2<<<(51 * WP + 102 + 255) / 256, 256, 0, stream>>>(
        We1, be1, b1, Wout, bout, Wc, Mc, cc, dd);

    // CSR build
    k_hist<<<(N_EDGES + 255) / 256, 256, 0, stream>>>(ei, deg);
    scan1<<<NBLK, 256, 0, stream>>>(deg, blksum);
    scan2<<<1, 256, 0, stream>>>(blksum, blkoff);
    scan3<<<NBLK, 256, 0, stream>>>(deg, blkoff, row_start, cursor);
    k_fill<<<(N_EDGES + 255) / 256, 256, 0, stream>>>(ei, cursor, eid_srt, src_srt);

    // S aggregation (gather)
    k_agg_S<<<(N_NODES + 3) / 4, 256, 0, stream>>>(ea, eid_srt, row_start, S);

    // layer 0
    k_layer0<<<(N_NODES + 127) / 128, 256, 0, stream>>>(x, W0, b0, S, deg, M0, c0, yb, hacc);
    k_agg_h<<<(N_NODES + 3) / 4, 256, 0, stream>>>(yb, src_srt, row_start, hacc);

    // layer 1 + output projection
    k_layer1<<<(N_NODES + 127) / 128, 256, 0, stream>>>(hacc, Wc, S, deg, Mc, cc, dd, wb, out);
    k_agg_out<<<(N_NODES + 3) / 4, 256, 0, stream>>>((const unsigned short*)wb, src_srt, row_start, out);
}

// Round 5
// 613.766 us; speedup vs baseline: 2.1405x; 1.1000x over previous
//
#include <hip/hip_runtime.h>

#define N_NODES 50000
#define N_EDGES 800000
#define IN_CH   151
#define HID     128
#define OUT_CH  51
#define EDIM    51
#define WP      64              // padded minor dim for Wc / Mc / w
#define LSTR    68              // LDS staging row stride (floats): 64 rows + 4 pad
#define NBLK    ((N_NODES + 255) / 256)   // 196 scan blocks

static __device__ __forceinline__ unsigned int f2bf(float f) {
    union { float f; unsigned int u; } v; v.f = f;
    unsigned int r = v.u + 0x7FFF + ((v.u >> 16) & 1);
    return r >> 16;
}
static __device__ __forceinline__ float bflo(unsigned int u) {
    return __uint_as_float(u << 16);
}
static __device__ __forceinline__ float bfhi(unsigned int u) {
    return __uint_as_float(u & 0xFFFF0000u);
}

// ---------- small weight-product kernels ----------
// M0 = W_edge0@W0 [51,128]; c0 = b_edge0@W0 [128]; Wc = W1@W_out padded [128,64]
__global__ void kw1(const float* __restrict__ We0, const float* __restrict__ W0,
                    const float* __restrict__ be0, const float* __restrict__ W1,
                    const float* __restrict__ Wout,
                    float* __restrict__ M0, float* __restrict__ c0, float* __restrict__ Wc) {
    int t = blockIdx.x * blockDim.x + threadIdx.x;
    if (t < 51 * 128) {
        int i = t / 128, j = t % 128;
        float a = 0.f;
        for (int k = 0; k < IN_CH; ++k) a += We0[i * IN_CH + k] * W0[k * HID + j];
        M0[t] = a;
    } else if (t < 51 * 128 + 128) {
        int j = t - 51 * 128;
        float a = 0.f;
        for (int k = 0; k < IN_CH; ++k) a += be0[k] * W0[k * HID + j];
        c0[j] = a;
    } else if (t < 51 * 128 + 128 + 128 * WP) {
        int u = t - (51 * 128 + 128);
        int i = u / WP, j = u % WP;
        float a = 0.f;
        if (j < OUT_CH)
            for (int k = 0; k < HID; ++k) a += W1[i * HID + k] * Wout[k * OUT_CH + j];
        Wc[i * WP + j] = a;
    }
}

// Mc = W_edge1@Wc padded [51,64]; cc = b_edge1@Wc [51]; dd = b1@W_out + b_out [51]
__global__ void kw2(const float* __restrict__ We1, const float* __restrict__ be1,
                    const float* __restrict__ b1, const float* __restrict__ Wout,
                    const float* __restrict__ bout, const float* __restrict__ Wc,
                    float* __restrict__ Mc, float* __restrict__ cc, float* __restrict__ dd) {
    int t = blockIdx.x * blockDim.x + threadIdx.x;
    if (t < 51 * WP) {
        int i = t / WP, j = t % WP;
        float a = 0.f;
        if (j < OUT_CH)
            for (int k = 0; k < HID; ++k) a += We1[i * HID + k] * Wc[k * WP + j];
        Mc[t] = a;
    } else if (t < 51 * WP + 51) {
        int j = t - 51 * WP;
        float a = 0.f;
        for (int k = 0; k < HID; ++k) a += be1[k] * Wc[k * WP + j];
        cc[j] = a;
    } else if (t < 51 * WP + 102) {
        int j = t - (51 * WP + 51);
        float a = 0.f;
        for (int k = 0; k < HID; ++k) a += b1[k] * Wout[k * OUT_CH + j];
        dd[j] = a + bout[j];
    }
}

// ---------- CSR build ----------
__global__ void k_hist(const int* __restrict__ ei, int* __restrict__ deg) {
    int e = blockIdx.x * 256 + threadIdx.x;
    if (e >= N_EDGES) return;
    atomicAdd(&deg[ei[N_EDGES + e]], 1);
}

__global__ void scan1(const int* __restrict__ deg, int* __restrict__ blksum) {
    __shared__ int lds[256];
    int i = blockIdx.x * 256 + threadIdx.x;
    lds[threadIdx.x] = (i < N_NODES) ? deg[i] : 0;
    __syncthreads();
    for (int s = 128; s > 0; s >>= 1) {
        if (threadIdx.x < s) lds[threadIdx.x] += lds[threadIdx.x + s];
        __syncthreads();
    }
    if (threadIdx.x == 0) blksum[blockIdx.x] = lds[0];
}

__global__ void scan2(const int* __restrict__ blksum, int* __restrict__ blkoff) {
    __shared__ int lds[256];
    int v = (threadIdx.x < NBLK) ? blksum[threadIdx.x] : 0;
    lds[threadIdx.x] = v;
    __syncthreads();
    for (int s = 1; s < 256; s <<= 1) {
        int t = (threadIdx.x >= s) ? lds[threadIdx.x - s] : 0;
        __syncthreads();
        lds[threadIdx.x] += t;
        __syncthreads();
    }
    if (threadIdx.x < NBLK) blkoff[threadIdx.x] = lds[threadIdx.x] - v;  // exclusive
}

__global__ void scan3(const int* __restrict__ deg, const int* __restrict__ blkoff,
                      int* __restrict__ row_start, int* __restrict__ cursor) {
    __shared__ int lds[256];
    int i = blockIdx.x * 256 + threadIdx.x;
    int v = (i < N_NODES) ? deg[i] : 0;
    lds[threadIdx.x] = v;
    __syncthreads();
    for (int s = 1; s < 256; s <<= 1) {
        int t = (threadIdx.x >= s) ? lds[threadIdx.x - s] : 0;
        __syncthreads();
        lds[threadIdx.x] += t;
        __syncthreads();
    }
    if (i < N_NODES) {
        int ex = blkoff[blockIdx.x] + lds[threadIdx.x] - v;
        row_start[i] = ex;
        cursor[i] = ex;
    }
    if (blockIdx.x == 0 && threadIdx.x == 0) row_start[N_NODES] = N_EDGES;
}

__global__ void k_fill(const int* __restrict__ ei, int* __restrict__ cursor,
                       int* __restrict__ eid_sorted, int* __restrict__ src_sorted) {
    int e = blockIdx.x * 256 + threadIdx.x;
    if (e >= N_EDGES) return;
    int dst = ei[N_EDGES + e];
    int pos = atomicAdd(&cursor[dst], 1);
    eid_sorted[pos] = e;
    src_sorted[pos] = ei[e];
}

// ---------- gather aggregations (8-deep MLP unroll) ----------
// S[n] = sum_{e: dst=n} edge_attr[e]
__global__ void k_agg_S(const float* __restrict__ ea, const int* __restrict__ eid_sorted,
                        const int* __restrict__ row_start, float* __restrict__ S) {
    int n = blockIdx.x * 4 + (threadIdx.x >> 6);
    if (n >= N_NODES) return;
    int lane = threadIdx.x & 63;
    int n0 = row_start[n], n1 = row_start[n + 1];
    float acc = 0.f;
    bool act = lane < EDIM;
    for (int base = n0; base < n1; base += 64) {
        int cnt = min(64, n1 - base);
        int eid_l = (base + lane < n1) ? eid_sorted[base + lane] : 0;
        int t = 0;
        for (; t + 8 <= cnt; t += 8) {
            int e0 = __shfl(eid_l, t),     e1 = __shfl(eid_l, t + 1);
            int e2 = __shfl(eid_l, t + 2), e3 = __shfl(eid_l, t + 3);
            int e4 = __shfl(eid_l, t + 4), e5 = __shfl(eid_l, t + 5);
            int e6 = __shfl(eid_l, t + 6), e7 = __shfl(eid_l, t + 7);
            float v0 = act ? ea[(size_t)e0 * EDIM + lane] : 0.f;
            float v1 = act ? ea[(size_t)e1 * EDIM + lane] : 0.f;
            float v2 = act ? ea[(size_t)e2 * EDIM + lane] : 0.f;
            float v3 = act ? ea[(size_t)e3 * EDIM + lane] : 0.f;
            float v4 = act ? ea[(size_t)e4 * EDIM + lane] : 0.f;
            float v5 = act ? ea[(size_t)e5 * EDIM + lane] : 0.f;
            float v6 = act ? ea[(size_t)e6 * EDIM + lane] : 0.f;
            float v7 = act ? ea[(size_t)e7 * EDIM + lane] : 0.f;
            acc += ((v0 + v1) + (v2 + v3)) + ((v4 + v5) + (v6 + v7));
        }
        for (; t < cnt; ++t) {
            int e0 = __shfl(eid_l, t);
            if (act) acc += ea[(size_t)e0 * EDIM + lane];
        }
    }
    if (act) S[(size_t)n * EDIM + lane] = acc;
}

// hacc[n] += sum_{e: dst=n} y[src[e]]   (y stored bf16, 2 ch per lane)
__global__ void k_agg_h(const unsigned int* __restrict__ yb, const int* __restrict__ src_sorted,
                        const int* __restrict__ row_start, float* __restrict__ hacc) {
    int n = blockIdx.x * 4 + (threadIdx.x >> 6);
    if (n >= N_NODES) return;
    int lane = threadIdx.x & 63;
    int n0 = row_start[n], n1 = row_start[n + 1];
    float2 acc = make_float2(0.f, 0.f);
    for (int base = n0; base < n1; base += 64) {
        int cnt = min(64, n1 - base);
        int s_l = (base + lane < n1) ? src_sorted[base + lane] : 0;
        int t = 0;
        for (; t + 8 <= cnt; t += 8) {
            int s0 = __shfl(s_l, t),     s1 = __shfl(s_l, t + 1);
            int s2 = __shfl(s_l, t + 2), s3 = __shfl(s_l, t + 3);
            int s4 = __shfl(s_l, t + 4), s5 = __shfl(s_l, t + 5);
            int s6 = __shfl(s_l, t + 6), s7 = __shfl(s_l, t + 7);
            unsigned int v0 = yb[(size_t)s0 * 64 + lane];
            unsigned int v1 = yb[(size_t)s1 * 64 + lane];
            unsigned int v2 = yb[(size_t)s2 * 64 + lane];
            unsigned int v3 = yb[(size_t)s3 * 64 + lane];
            unsigned int v4 = yb[(size_t)s4 * 64 + lane];
            unsigned int v5 = yb[(size_t)s5 * 64 + lane];
            unsigned int v6 = yb[(size_t)s6 * 64 + lane];
            unsigned int v7 = yb[(size_t)s7 * 64 + lane];
            acc.x += ((bflo(v0) + bflo(v1)) + (bflo(v2) + bflo(v3)))
                   + ((bflo(v4) + bflo(v5)) + (bflo(v6) + bflo(v7)));
            acc.y += ((bfhi(v0) + bfhi(v1)) + (bfhi(v2) + bfhi(v3)))
                   + ((bfhi(v4) + bfhi(v5)) + (bfhi(v6) + bfhi(v7)));
        }
        for (; t < cnt; ++t) {
            int s0 = __shfl(s_l, t);
            unsigned int v0 = yb[(size_t)s0 * 64 + lane];
            acc.x += bflo(v0); acc.y += bfhi(v0);
        }
    }
    float2* hp = (float2*)(hacc + (size_t)n * HID) + lane;
    float2 old = *hp;
    old.x += acc.x; old.y += acc.y;
    *hp = old;
}

// out[n] += sum_{e: dst=n} w[src[e]]   (w stored bf16, padded to 64)
__global__ void k_agg_out(const unsigned short* __restrict__ wb, const int* __restrict__ src_sorted,
                          const int* __restrict__ row_start, float* __restrict__ out) {
    int n = blockIdx.x * 4 + (threadIdx.x >> 6);
    if (n >= N_NODES) return;
    int lane = threadIdx.x & 63;
    int n0 = row_start[n], n1 = row_start[n + 1];
    float acc = 0.f;
    bool act = lane < OUT_CH;
    for (int base = n0; base < n1; base += 64) {
        int cnt = min(64, n1 - base);
        int s_l = (base + lane < n1) ? src_sorted[base + lane] : 0;
        int t = 0;
        for (; t + 8 <= cnt; t += 8) {
            int s0 = __shfl(s_l, t),     s1 = __shfl(s_l, t + 1);
            int s2 = __shfl(s_l, t + 2), s3 = __shfl(s_l, t + 3);
            int s4 = __shfl(s_l, t + 4), s5 = __shfl(s_l, t + 5);
            int s6 = __shfl(s_l, t + 6), s7 = __shfl(s_l, t + 7);
            unsigned int v0 = act ? wb[(size_t)s0 * WP + lane] : 0u;
            unsigned int v1 = act ? wb[(size_t)s1 * WP + lane] : 0u;
            unsigned int v2 = act ? wb[(size_t)s2 * WP + lane] : 0u;
            unsigned int v3 = act ? wb[(size_t)s3 * WP + lane] : 0u;
            unsigned int v4 = act ? wb[(size_t)s4 * WP + lane] : 0u;
            unsigned int v5 = act ? wb[(size_t)s5 * WP + lane] : 0u;
            unsigned int v6 = act ? wb[(size_t)s6 * WP + lane] : 0u;
            unsigned int v7 = act ? wb[(size_t)s7 * WP + lane] : 0u;
            acc += ((bflo(v0) + bflo(v1)) + (bflo(v2) + bflo(v3)))
                 + ((bflo(v4) + bflo(v5)) + (bflo(v6) + bflo(v7)));
        }
        for (; t < cnt; ++t) {
            int s0 = __shfl(s_l, t);
            if (act) acc += bflo((unsigned int)wb[(size_t)s0 * WP + lane]);
        }
    }
    if (act) out[(size_t)n * OUT_CH + lane] += acc;
}

// ---------- layer-0 tiled GEMM: y(bf16) = x@W0 ; hacc = y + S@M0 + (deg+1)*c0 + b0 ----------
// block = 64 rows x 128 cols (782 blocks); thread tile 4 rows x 8 cols; 17.4 KB LDS.
__global__ __launch_bounds__(256, 4) void k_layer0(
        const float* __restrict__ x, const float* __restrict__ W0,
        const float* __restrict__ b0, const float* __restrict__ S,
        const int* __restrict__ deg, const float* __restrict__ M0,
        const float* __restrict__ c0,
        unsigned int* __restrict__ yb, float* __restrict__ hacc) {
    __shared__ float aT[64 * LSTR];   // 17,408 B
    int tid = threadIdx.x;
    int r_base = blockIdx.x * 64;
    int cg = tid & 15, rg = tid >> 4;
    int c = cg * 8, r0 = rg * 4;

    float4 accA[4], accB[4];
#pragma unroll
    for (int i = 0; i < 4; ++i) {
        accA[i] = make_float4(0.f, 0.f, 0.f, 0.f);
        accB[i] = make_float4(0.f, 0.f, 0.f, 0.f);
    }

    // ---- x phases: k = 0..150 in chunks of 64 ----
    for (int p = 0; p < 3; ++p) {
        int koff = p * 64;
        int chunk = min(64, IN_CH - koff);
        __syncthreads();
        for (int idx = tid; idx < 64 * 64; idx += 256) {
            int r = idx >> 6, kk = idx & 63;
            if (kk >= chunk) continue;
            int row = r_base + r;
            aT[kk * LSTR + r] = (row < N_NODES) ? x[(size_t)row * IN_CH + koff + kk] : 0.f;
        }
        __syncthreads();
#pragma unroll 4
        for (int kk = 0; kk < chunk; ++kk) {
            int k = koff + kk;
            float4 wv0 = *(const float4*)(W0 + k * HID + c);
            float4 wv1 = *(const float4*)(W0 + k * HID + c + 4);
            float4 a0 = *(const float4*)(&aT[kk * LSTR + r0]);
            float ar[4] = {a0.x, a0.y, a0.z, a0.w};
#pragma unroll
            for (int i = 0; i < 4; ++i) {
                accA[i].x += ar[i] * wv0.x; accA[i].y += ar[i] * wv0.y;
                accA[i].z += ar[i] * wv0.z; accA[i].w += ar[i] * wv0.w;
                accB[i].x += ar[i] * wv1.x; accB[i].y += ar[i] * wv1.y;
                accB[i].z += ar[i] * wv1.z; accB[i].w += ar[i] * wv1.w;
            }
        }
    }

    // ---- store y as bf16 ----
#pragma unroll
    for (int i = 0; i < 4; ++i) {
        int row = r_base + r0 + i;
        if (row < N_NODES) {
            uint4 pk;
            pk.x = f2bf(accA[i].x) | (f2bf(accA[i].y) << 16);
            pk.y = f2bf(accA[i].z) | (f2bf(accA[i].w) << 16);
            pk.z = f2bf(accB[i].x) | (f2bf(accB[i].y) << 16);
            pk.w = f2bf(accB[i].z) | (f2bf(accB[i].w) << 16);
            *(uint4*)(yb + (size_t)row * 64 + (c >> 1)) = pk;
        }
    }

    // ---- S phase: k = 0..50 ----
    __syncthreads();
    for (int idx = tid; idx < 64 * 64; idx += 256) {
        int r = idx >> 6, kk = idx & 63;
        if (kk >= EDIM) continue;
        int row = r_base + r;
        aT[kk * LSTR + r] = (row < N_NODES) ? S[(size_t)row * EDIM + kk] : 0.f;
    }
    __syncthreads();
#pragma unroll 4
    for (int kk = 0; kk < EDIM; ++kk) {
        float4 wv0 = *(const float4*)(M0 + kk * HID + c);
        float4 wv1 = *(const float4*)(M0 + kk * HID + c + 4);
        float4 a0 = *(const float4*)(&aT[kk * LSTR + r0]);
        float ar[4] = {a0.x, a0.y, a0.z, a0.w};
#pragma unroll
        for (int i = 0; i < 4; ++i) {
            accA[i].x += ar[i] * wv0.x; accA[i].y += ar[i] * wv0.y;
            accA[i].z += ar[i] * wv0.z; accA[i].w += ar[i] * wv0.w;
            accB[i].x += ar[i] * wv1.x; accB[i].y += ar[i] * wv1.y;
            accB[i].z += ar[i] * wv1.z; accB[i].w += ar[i] * wv1.w;
        }
    }

    // ---- epilogue: hacc = acc + (deg+1)*c0 + b0 (fp32) ----
    float4 cv0 = *(const float4*)(c0 + c);
    float4 cv1 = *(const float4*)(c0 + c + 4);
    float4 bv0 = *(const float4*)(b0 + c);
    float4 bv1 = *(const float4*)(b0 + c + 4);
#pragma unroll
    for (int i = 0; i < 4; ++i) {
        int row = r_base + r0 + i;
        if (row < N_NODES) {
            float d1 = (float)(deg[row] + 1);
            float4 vA = accA[i], vB = accB[i];
            vA.x += d1 * cv0.x + bv0.x; vA.y += d1 * cv0.y + bv0.y;
            vA.z += d1 * cv0.z + bv0.z; vA.w += d1 * cv0.w + bv0.w;
            vB.x += d1 * cv1.x + bv1.x; vB.y += d1 * cv1.y + bv1.y;
            vB.z += d1 * cv1.z + bv1.z; vB.w += d1 * cv1.w + bv1.w;
            *(float4*)(hacc + (size_t)row * HID + c) = vA;
            *(float4*)(hacc + (size_t)row * HID + c + 4) = vB;
        }
    }
}

// ---------- layer-1 tiled GEMM: w(bf16) = hacc@Wc ; out = w + S@Mc + (deg+1)*cc + dd ----------
// block = 64 rows x 64 cols (52 live, 782 blocks); thread tile 4x4; 17.4 KB LDS.
__global__ __launch_bounds__(256, 4) void k_layer1(
        const float* __restrict__ hacc, const float* __restrict__ Wc,
        const float* __restrict__ S, const int* __restrict__ deg,
        const float* __restrict__ Mc, const float* __restrict__ cc,
        const float* __restrict__ dd,
        unsigned int* __restrict__ wb, float* __restrict__ out) {
    __shared__ float aT[64 * LSTR];
    int tid = threadIdx.x;
    int r_base = blockIdx.x * 64;
    int cg = tid & 15, rg = tid >> 4;
    int c = cg * 4, r0 = rg * 4;

    float4 acc[4];
#pragma unroll
    for (int i = 0; i < 4; ++i) acc[i] = make_float4(0.f, 0.f, 0.f, 0.f);

    // ---- h phases: k = 0..127 in chunks of 64 ----
    for (int p = 0; p < 2; ++p) {
        int koff = p * 64;
        __syncthreads();
        for (int idx = tid; idx < 64 * 64; idx += 256) {
            int r = idx >> 6, kk = idx & 63;
            int row = r_base + r;
            aT[kk * LSTR + r] = (row < N_NODES) ? hacc[(size_t)row * HID + koff + kk] : 0.f;
        }
        __syncthreads();
#pragma unroll 4
        for (int kk = 0; kk < 64; ++kk) {
            int k = koff + kk;
            float4 wv = *(const float4*)(Wc + k * WP + c);
            float4 a0 = *(const float4*)(&aT[kk * LSTR + r0]);
            float ar[4] = {a0.x, a0.y, a0.z, a0.w};
#pragma unroll
            for (int i = 0; i < 4; ++i) {
                acc[i].x += ar[i] * wv.x; acc[i].y += ar[i] * wv.y;
                acc[i].z += ar[i] * wv.z; acc[i].w += ar[i] * wv.w;
            }
        }
    }

    // ---- store w as bf16 (padded 64) ----
#pragma unroll
    for (int i = 0; i < 4; ++i) {
        int row = r_base + r0 + i;
        if (row < N_NODES) {
            uint2 pk;
            pk.x = f2bf(acc[i].x) | (f2bf(acc[i].y) << 16);
            pk.y = f2bf(acc[i].z) | (f2bf(acc[i].w) << 16);
            *(uint2*)(wb + (size_t)row * 32 + (c >> 1)) = pk;
        }
    }

    // ---- S phase ----
    __syncthreads();
    for (int idx = tid; idx < 64 * 64; idx += 256) {
        int r = idx >> 6, kk = idx & 63;
        if (kk >= EDIM) continue;
        int row = r_base + r;
        aT[kk * LSTR + r] = (row < N_NODES) ? S[(size_t)row * EDIM + kk] : 0.f;
    }
    __syncthreads();
#pragma unroll 4
    for (int kk = 0; kk < EDIM; ++kk) {
        float4 wv = *(const float4*)(Mc + kk * WP + c);
        float4 a0 = *(const float4*)(&aT[kk * LSTR + r0]);
        float ar[4] = {a0.x, a0.y, a0.z, a0.w};
#pragma unroll
        for (int i = 0; i < 4; ++i) {
            acc[i].x += ar[i] * wv.x; acc[i].y += ar[i] * wv.y;
            acc[i].z += ar[i] * wv.z; acc[i].w += ar[i] * wv.w;
        }
    }

    // ---- epilogue: out = acc + (deg+1)*cc + dd, cols < 51 ----
    if (c < OUT_CH) {
        float cv[4], dv[4];
#pragma unroll
        for (int j = 0; j < 4; ++j) {
            int col = c + j;
            cv[j] = (col < OUT_CH) ? cc[col] : 0.f;
            dv[j] = (col < OUT_CH) ? dd[col] : 0.f;
        }
#pragma unroll
        for (int i = 0; i < 4; ++i) {
            int row = r_base + r0 + i;
            if (row < N_NODES) {
                float d1 = (float)(deg[row] + 1);
                const float* ap = (const float*)&acc[i];
#pragma unroll
                for (int j = 0; j < 4; ++j) {
                    int col = c + j;
                    if (col < OUT_CH)
                        out[(size_t)row * OUT_CH + col] = ap[j] + d1 * cv[j] + dv[j];
                }
            }
        }
    }
}

extern "C" void kernel_launch(void* const* d_in, const int* in_sizes, int n_in,
                              void* d_out, int out_size, void* d_ws, size_t ws_size,
                              hipStream_t stream) {
    const float* x    = (const float*)d_in[0];
    const float* ea   = (const float*)d_in[1];
    const float* We0  = (const float*)d_in[2];
    const float* be0  = (const float*)d_in[3];
    const float* W0   = (const float*)d_in[4];
    const float* b0   = (const float*)d_in[5];
    const float* We1  = (const float*)d_in[6];
    const float* be1  = (const float*)d_in[7];
    const float* W1   = (const float*)d_in[8];
    const float* b1   = (const float*)d_in[9];
    const float* Wout = (const float*)d_in[10];
    const float* bout = (const float*)d_in[11];
    const int*   ei   = (const int*)d_in[12];
    float* out = (float*)d_out;

    char* p = (char*)d_ws;
    auto alloc = [&](size_t bytes) {
        char* r = p;
        p += (bytes + 255) & ~(size_t)255;
        return r;
    };
    float* S         = (float*)alloc((size_t)N_NODES * EDIM * 4);    // 10.2 MB
    int*   deg       = (int*)  alloc((size_t)N_NODES * 4);
    int*   row_start = (int*)  alloc((size_t)(N_NODES + 1) * 4);
    int*   cursor    = (int*)  alloc((size_t)N_NODES * 4);
    int*   blksum    = (int*)  alloc((size_t)NBLK * 4);
    int*   blkoff    = (int*)  alloc((size_t)NBLK * 4);
    int*   eid_srt   = (int*)  alloc((size_t)N_EDGES * 4);           // 3.2 MB
    int*   src_srt   = (int*)  alloc((size_t)N_EDGES * 4);           // 3.2 MB
    unsigned int* yb = (unsigned int*)alloc((size_t)N_NODES * 64 * 4);  // y bf16: 12.8 MB
    float* hacc      = (float*)alloc((size_t)N_NODES * HID * 4);     // 25.6 MB
    unsigned int* wb = (unsigned int*)alloc((size_t)N_NODES * 32 * 4);  // w bf16: 6.4 MB
    float* M0        = (float*)alloc(51 * 128 * 4);
    float* c0        = (float*)alloc(128 * 4);
    float* Wc        = (float*)alloc(128 * WP * 4);
    float* Mc        = (float*)alloc(51 * WP * 4);
    float* cc        = (float*)alloc(51 * 4);
    float* dd        = (float*)alloc(51 * 4);

    hipMemsetAsync(deg, 0, (size_t)N_NODES * 4, stream);

    kw1<<<(51 * 128 + 128 + 128 * WP + 255) / 256, 256, 0, stream>>>(
        We0, W0, be0, W1, Wout, M0, c0, Wc);
    kw2<<<(51 * WP + 102 + 255) / 256, 256, 0, stream>>>(
        We1, be1, b1, Wout, bout, Wc, Mc, cc, dd);

    // CSR build
    k_hist<<<(N_EDGES + 255) / 256, 256, 0, stream>>>(ei, deg);
    scan1<<<NBLK, 256, 0, stream>>>(deg, blksum);
    scan2<<<1, 256, 0, stream>>>(blksum, blkoff);
    scan3<<<NBLK, 256, 0, stream>>>(deg, blkoff, row_start, cursor);
    k_fill<<<(N_EDGES + 255) / 256, 256, 0, stream>>>(ei, cursor, eid_srt, src_srt);

    // S aggregation (gather)
    k_agg_S<<<(N_NODES + 3) / 4, 256, 0, stream>>>(ea, eid_srt, row_start, S);

    // layer 0
    k_layer0<<<(N_NODES + 63) / 64, 256, 0, stream>>>(x, W0, b0, S, deg, M0, c0, yb, hacc);
    k_agg_h<<<(N_NODES + 3) / 4, 256, 0, stream>>>(yb, src_srt, row_start, hacc);

    // layer 1 + output projection
    k_layer1<<<(N_NODES + 63) / 64, 256, 0, stream>>>(hacc, Wc, S, deg, Mc, cc, dd, wb, out);
    k_agg_out<<<(N_NODES + 3) / 4, 256, 0, stream>>>((const unsigned short*)wb, src_srt, row_start, out);
}